// Round 9
// baseline (207.771 us; speedup 1.0000x reference)
//
#include <hip/hip_runtime.h>
#include <hip/hip_bf16.h>

#define BATCH   2
#define SEQ     4096
#define DMODEL  512
#define DINNER  1024
#define DSTATE  64
#define NHEADS  16
#define HEADDIM 64
#define CONVDIM 1152
#define NPROJ   2192
#define NPROJ_PAD 2304        // 18*128 — exact tile grid for gemm0
#define MROWS   (BATCH*SEQ)   // 8192
#define QCH     64
#define NCHUNK  (SEQ/QCH)     // 64 chunks per batch
#define NMT     (MROWS/128)   // 64 m-tiles

typedef short bf16x8 __attribute__((ext_vector_type(8)));
typedef float f32x4  __attribute__((ext_vector_type(4)));
using bf16 = __hip_bfloat16;
typedef unsigned short ushort_t;
typedef unsigned int   uint_t;

__device__ __forceinline__ float sigmoidf_(float x) { return 1.f / (1.f + __expf(-x)); }
__device__ __forceinline__ float bf2f(ushort_t u) { return __uint_as_float((uint_t)u << 16); }
__device__ __forceinline__ ushort_t f2bfu(float f) {
    bf16 h = __float2bfloat16(f);
    return *(ushort_t*)&h;
}
__device__ __forceinline__ void bf8_to_f(const ushort_t* __restrict__ p, float* __restrict__ f) {
    uint4 u = *(const uint4*)p;
    f[0] = __uint_as_float((u.x & 0xFFFFu) << 16);
    f[1] = __uint_as_float(u.x & 0xFFFF0000u);
    f[2] = __uint_as_float((u.y & 0xFFFFu) << 16);
    f[3] = __uint_as_float(u.y & 0xFFFF0000u);
    f[4] = __uint_as_float((u.z & 0xFFFFu) << 16);
    f[5] = __uint_as_float(u.z & 0xFFFF0000u);
    f[6] = __uint_as_float((u.w & 0xFFFFu) << 16);
    f[7] = __uint_as_float(u.w & 0xFFFF0000u);
}
__device__ __forceinline__ uint4 f8_to_bf(const float* __restrict__ f) {
    union { ushort_t s[8]; uint4 u; } r;
#pragma unroll
    for (int i = 0; i < 8; i++) r.s[i] = f2bfu(f[i]);
    return r.u;
}

// async global->LDS, 16B per lane; lds dest is wave-uniform base + lane*16
__device__ __forceinline__ void gload_lds16(const ushort_t* g, ushort_t* l)
{
    __builtin_amdgcn_global_load_lds(
        (const __attribute__((address_space(1))) void*)g,
        (__attribute__((address_space(3)))       void*)l,
        16, 0, 0);
}

// ---------------------------------------------------------------- merged prep: cast x + transpose W_in + transpose W_out
// blocks [0,2048): cast fp32->bf16, 8 elems/thread
// blocks [2048,3200): W_in^T (512x2192 -> 2304x512, zero-pad)
// blocks [3200,3712): W_out^T scaled by norm_weight (1024x512 -> 512x1024)
__global__ __launch_bounds__(256, 4)
void prep_k(const float* __restrict__ x, ushort_t* __restrict__ xb,
            const float* __restrict__ W_in, ushort_t* __restrict__ WinT,
            const float* __restrict__ W_out, ushort_t* __restrict__ WoutT,
            const float* __restrict__ nw)
{
    __shared__ __align__(16) ushort_t tile[32][33];
    const int bid = blockIdx.x, tid = threadIdx.x;
    if (bid < 2048) {
        int i = bid * 256 + tid;                    // n8 = 524288 exactly
        float f[8];
        *(float4*)(f + 0) = ((const float4*)x)[i * 2 + 0];
        *(float4*)(f + 4) = ((const float4*)x)[i * 2 + 1];
        ((uint4*)xb)[i] = f8_to_bf(f);
        return;
    }
    const int tx = tid & 31, ty = tid >> 5;         // 32 x 8
    const float* in; ushort_t* out; int R, C, Cpad; const float* sv;
    int bx, by;
    if (bid < 3200) {
        int b2 = bid - 2048;                        // grid (72, 16)
        bx = b2 % (NPROJ_PAD / 32); by = b2 / (NPROJ_PAD / 32);
        in = W_in; out = WinT; R = DMODEL; C = NPROJ; Cpad = NPROJ_PAD; sv = nullptr;
    } else {
        int b3 = bid - 3200;                        // grid (16, 32)
        bx = b3 % (DMODEL / 32); by = b3 / (DMODEL / 32);
        in = W_out; out = WoutT; R = DINNER; C = DMODEL; Cpad = DMODEL; sv = nw;
    }
    int c0 = bx * 32, r0 = by * 32;
#pragma unroll
    for (int i = 0; i < 32; i += 8) {
        int r = r0 + ty + i, c = c0 + tx;
        float v = (r < R && c < C) ? in[(size_t)r * C + c] : 0.f;
        if (sv && r < R) v *= sv[r];
        tile[ty + i][tx] = f2bfu(v);
    }
    __syncthreads();
#pragma unroll
    for (int i = 0; i < 32; i += 8) {
        int orow = c0 + ty + i, ocol = r0 + tx;
        if (orow < Cpad && ocol < R) out[(size_t)orow * R + ocol] = tile[tx][ty + i];
    }
}

// ---------------------------------------------------------------- conv_k: B/C conv+SiLU  +  x-conv boundary fixup
// blocks [0,512): bcconv (unchanged)
// blocks [512,608): xfix — conv+silu for tile rows {0,1,2} of each of the 64
//   m-tiles, using the raw pre-conv boundary rows gemm0 dumped into xbnd
//   (xbnd[mt][0..2] = tile rows 0..2; xbnd[mt][3..5] = tile rows 125..127).
__global__ __launch_bounds__(256, 4)
void conv_k(const ushort_t* __restrict__ xpbc, const ushort_t* __restrict__ xbnd,
            const float* __restrict__ cw, const float* __restrict__ cb,
            ushort_t* __restrict__ bcc, ushort_t* __restrict__ xs)
{
    const int bid = blockIdx.x, tid = threadIdx.x;
    if (bid < 512) {
        int idx = bid * 256 + tid;                   // MROWS*16
        int row = idx >> 4, c8 = (idx & 15) * 8;
        int l = row & (SEQ - 1);
        float acc[8];
#pragma unroll
        for (int i = 0; i < 8; i++) acc[i] = cb[1024 + c8 + i];
#pragma unroll
        for (int j = 0; j < 4; j++) {
            int ll = l - 3 + j;
            if (ll >= 0) {
                float v[8];
                bf8_to_f(xpbc + (size_t)(row - 3 + j) * 128 + c8, v);
#pragma unroll
                for (int i = 0; i < 8; i++) acc[i] += cw[(1024 + c8 + i) * 4 + j] * v[i];
            }
        }
#pragma unroll
        for (int i = 0; i < 8; i++) { float v = acc[i]; acc[i] = v * sigmoidf_(v); }
        *(uint4*)(bcc + (size_t)row * 128 + c8) = f8_to_bf(acc);
        return;
    }
    // xfix: 192 boundary rows (3 per m-tile) x 1024 channels
    int idx = (bid - 512) * 256 + tid;               // 24576
    const int c8 = (idx & 127) * 8;
    const int rowid = idx >> 7;                      // 0..191
    const int mt = rowid / 3, t = rowid - mt * 3;    // tile, tile-row 0..2
    const int l = (mt * 128 + t) & (SEQ - 1);
    float acc[8];
#pragma unroll
    for (int i = 0; i < 8; i++) acc[i] = cb[c8 + i];
#pragma unroll
    for (int j = 0; j < 4; j++) {
        int ll = l - 3 + j;
        if (ll >= 0) {
            int tapidx = t - 3 + j;                  // -3..2
            const ushort_t* src = (tapidx >= 0)
                ? &xbnd[((size_t)mt * 6 + tapidx) * 1024 + c8]
                : &xbnd[((size_t)(mt - 1) * 6 + tapidx + 6) * 1024 + c8];
            float v[8];
            bf8_to_f(src, v);
#pragma unroll
            for (int i = 0; i < 8; i++) acc[i] += cw[(c8 + i) * 4 + j] * v[i];
        }
    }
    float o[8];
#pragma unroll
    for (int i = 0; i < 8; i++) { float v = acc[i]; o[i] = v * sigmoidf_(v); }
    *(uint4*)(xs + ((size_t)mt * 128 + t) * 1024 + c8) = f8_to_bf(o);
}

// ---------------------------------------------------------------- GEMM (bf16 MFMA), m97 structure + XCD swizzle.
// MODE 0: in-proj (TN=128). x-tiles (1024<=n0<2048) get a FUSED depthwise
//   conv+SiLU epilogue (rows 3..127 from the Cs tile; raw boundary rows
//   {0,1,2,125,126,127} dumped to xbnd for conv_k's fixup) — eliminates the
//   16MB xpre write + 19MB conv re-read. dt tile -> dtv/dalog planes.
// MODE 1: out-proj (TN=64) with FUSED RMSNorm (row ssq from A-fragments;
//   nw folded into Bt).
template<int MODE>
__global__ __launch_bounds__(256, MODE == 1 ? 4 : 3)
void gemm_k(const ushort_t* __restrict__ A, const ushort_t* __restrict__ Bt,
            ushort_t* __restrict__ zbuf, ushort_t* __restrict__ xs,
            ushort_t* __restrict__ xbnd, ushort_t* __restrict__ xpbc,
            float* __restrict__ dtv, float* __restrict__ dalog,
            const float* __restrict__ dt_b, const float* __restrict__ A_log,
            const float* __restrict__ cw, const float* __restrict__ cb,
            float* __restrict__ outf, int M, int N, int K)
{
    constexpr int TN = (MODE == 1) ? 64 : 128;   // block n-extent
    constexpr int NJ = TN / 32;                  // n-frags per wave (2 or 4)
    constexpr int SC = 132;
    constexpr int SMEM_ELTS = (MODE == 1) ? (128 * 64 + TN * 64) : (128 * SC);
    __shared__ __align__(16) ushort_t smem[SMEM_ELTS];
    ushort_t* As = smem;
    ushort_t* Bs = smem + 128 * 64;
    ushort_t* Cs = smem;

    const int tid  = threadIdx.x;
    const int wave = tid >> 6, lane = tid & 63;
    const int quad = lane >> 4, l16 = lane & 15;
    const int wm = (wave >> 1) * 64, wn = (wave & 1) * (TN / 2);

    // XCD-aware swizzle (nwg % 8 == 0 for both modes -> bijective)
    const int GX = gridDim.x;
    int lin = blockIdx.y * GX + blockIdx.x;
    const int cpx = (GX * gridDim.y) >> 3;
    lin = (lin & 7) * cpx + (lin >> 3);
    const int m0 = (lin / GX) * 128, n0 = (lin % GX) * TN;

    // staging: each gload_lds16 writes 1KB of LDS = 8 rows x 64 bf16 (lane l -> row l/8, elems (l&7)*8)
    const int srow = lane >> 3;          // 0..7
    const int scol = (lane & 7) * 8;     // 0,8,..,56
    const ushort_t* ag = A  + (size_t)(m0 + wave * 32       + srow) * K + scol;
    const ushort_t* bg = Bt + (size_t)(n0 + wave * (TN / 4) + srow) * K + scol;
    ushort_t* al = As + wave * 32 * 64;
    ushort_t* bl = Bs + wave * (TN / 4) * 64;

    f32x4 acc[4][NJ];
#pragma unroll
    for (int i = 0; i < 4; i++)
#pragma unroll
        for (int j = 0; j < NJ; j++) acc[i][j] = (f32x4){0.f, 0.f, 0.f, 0.f};
    float ssq4[4] = {0.f, 0.f, 0.f, 0.f};   // MODE 1: row sum-of-squares partials

    for (int k0 = 0; k0 < K; k0 += 64) {
        __syncthreads();                       // previous compute done before overwrite
#pragma unroll
        for (int j = 0; j < 4; j++)
            gload_lds16(ag + (size_t)(j * 8) * K + k0, al + j * 8 * 64);
#pragma unroll
        for (int j = 0; j < NJ; j++)
            gload_lds16(bg + (size_t)(j * 8) * K + k0, bl + j * 8 * 64);
        __syncthreads();                       // vmcnt(0) drained here -> tile ready
#pragma unroll
        for (int kk = 0; kk < 64; kk += 32) {
            bf16x8 af[4], bfr[NJ];
#pragma unroll
            for (int i = 0; i < 4; i++)
                af[i] = *(const bf16x8*)(&As[(wm + i * 16 + l16) * 64 + kk + quad * 8]);
#pragma unroll
            for (int j = 0; j < NJ; j++)
                bfr[j] = *(const bf16x8*)(&Bs[(wn + j * 16 + l16) * 64 + kk + quad * 8]);
#pragma unroll
            for (int i = 0; i < 4; i++)
#pragma unroll
                for (int j = 0; j < NJ; j++)
                    acc[i][j] = __builtin_amdgcn_mfma_f32_16x16x32_bf16(af[i], bfr[j], acc[i][j], 0, 0, 0);
            if (MODE == 1 && (wave & 1) == 0) {
#pragma unroll
                for (int i = 0; i < 4; i++)
#pragma unroll
                    for (int e = 0; e < 8; e++) {
                        float f = bf2f((ushort_t)af[i][e]);
                        ssq4[i] += f * f;
                    }
            }
        }
    }
    if (MODE == 1) {
        __syncthreads();                       // all LDS reads done; smem reused for row scales
        float* smemf = (float*)smem;
        if ((wave & 1) == 0) {
#pragma unroll
            for (int i = 0; i < 4; i++) {
                float s = ssq4[i];
                s += __shfl_xor(s, 16, 64);    // reduce over quads (cols)
                s += __shfl_xor(s, 32, 64);
                if (quad == 0) smemf[wm + i * 16 + l16] = s;
            }
        }
        __syncthreads();
#pragma unroll
        for (int i = 0; i < 4; i++)
#pragma unroll
            for (int j = 0; j < NJ; j++) {
                int col  = n0 + wn + j * 16 + l16;
                int rowl = wm + i * 16 + quad * 4;
#pragma unroll
                for (int r = 0; r < 4; r++) {
                    float sc = rsqrtf(smemf[rowl + r] * (1.f / DINNER) + 1e-5f);
                    outf[(size_t)(m0 + rowl + r) * N + col] = acc[i][j][r] * sc;
                }
            }
    } else if (n0 == 2176) {
        // dt head-block: dtv/dalog stored as [head][row] planes -> 16B-contiguous writes
#pragma unroll
        for (int i = 0; i < 4; i++)
#pragma unroll
            for (int j = 0; j < NJ; j++) {
                int col = n0 + wn + j * 16 + l16;
                int rowb = m0 + wm + i * 16 + quad * 4;
                if (col < N) {
                    int hh = col - 2176;
#pragma unroll
                    for (int r = 0; r < 4; r++) {
                        float v = acc[i][j][r];
                        size_t g = (size_t)hh * MROWS + (rowb + r);
                        float raw = v + dt_b[hh];
                        float sp  = (raw > 20.f) ? raw : log1pf(__expf(raw));
                        dtv  [g] = sp;
                        dalog[g] = -__expf(A_log[hh]) * sp;
                    }
                }
            }
    } else {
        __syncthreads();                       // all fragment reads done before Cs overlays As/Bs
#pragma unroll
        for (int i = 0; i < 4; i++)
#pragma unroll
            for (int j = 0; j < NJ; j++)
#pragma unroll
                for (int r = 0; r < 4; r++)
                    Cs[(wm + i * 16 + quad * 4 + r) * SC + wn + j * 16 + l16] = f2bfu(acc[i][j][r]);
        __syncthreads();
        if (MODE == 0 && n0 >= 1024 && n0 < 2048) {
            // fused x depthwise conv+SiLU epilogue.
            // thread covers fixed channel group cq, rows stride-16 over jj.
            const int cq  = (tid & 15) * 8;            // tile-local channel*8
            const int gch = (n0 - 1024) + cq;          // global channel base
            const int mt  = m0 >> 7;
            float wv[4][8], cbv[8];
#pragma unroll
            for (int i = 0; i < 8; i++) {
                cbv[i] = cb[gch + i];
                float4 w4 = *(const float4*)(cw + (size_t)(gch + i) * 4);
                wv[0][i] = w4.x; wv[1][i] = w4.y; wv[2][i] = w4.z; wv[3][i] = w4.w;
            }
#pragma unroll
            for (int jj = 0; jj < 8; jj++) {
                int row = jj * 16 + (tid >> 4);        // 0..127
                // boundary dump: raw pre-conv rows 0..2 and 125..127
                if (row < 3)
                    *(uint4*)&xbnd[((size_t)mt * 6 + row) * 1024 + gch] =
                        *(const uint4*)&Cs[row * SC + cq];
                else if (row >= 125)
                    *(uint4*)&xbnd[((size_t)mt * 6 + (row - 122)) * 1024 + gch] =
                        *(const uint4*)&Cs[row * SC + cq];
                if (row >= 3) {
                    // taps are fully in-tile and never cross a batch start
                    // (batch starts are tile-aligned, so l>=3 whenever row>=3)
                    float v0[8], v1[8], v2[8], v3[8], o[8];
                    bf8_to_f(&Cs[(row - 3) * SC + cq], v0);
                    bf8_to_f(&Cs[(row - 2) * SC + cq], v1);
                    bf8_to_f(&Cs[(row - 1) * SC + cq], v2);
                    bf8_to_f(&Cs[(row    ) * SC + cq], v3);
#pragma unroll
                    for (int i = 0; i < 8; i++) {
                        float a = cbv[i] + wv[0][i] * v0[i] + wv[1][i] * v1[i]
                                         + wv[2][i] * v2[i] + wv[3][i] * v3[i];
                        o[i] = a * sigmoidf_(a);
                    }
                    *(uint4*)&xs[(size_t)(m0 + row) * 1024 + gch] = f8_to_bf(o);
                }
            }
        } else {
            ushort_t* dst; int ld, coff;
            if (n0 < 1024) { dst = zbuf; ld = 1024; coff = n0; }
            else           { dst = xpbc; ld = 128;  coff = 0; }
#pragma unroll
            for (int jj = 0; jj < 8; jj++) {
                int idx = jj * 256 + tid;
                int row = idx >> 4, cq = (idx & 15) * 8;
                uint4 v = *(const uint4*)&Cs[row * SC + cq];
                *(uint4*)&dst[(size_t)(m0 + row) * ld + coff + cq] = v;
            }
        }
    }
}

// ---------------------------------------------------------------- per-chunk state outer product (MFMA)
// Transposed LDS tiles use col-XOR swizzle t' = t ^ ((p>>4)<<4).
__global__ __launch_bounds__(256, 3)
void chunk_state_k(const ushort_t* __restrict__ xs, const ushort_t* __restrict__ bcc,
                   const float* __restrict__ dtv, const float* __restrict__ dalog,
                   ushort_t* __restrict__ statesT, float* __restrict__ cdecay)
{
    const int c = blockIdx.x, h = blockIdx.y, b = blockIdx.z;
    __shared__ __align__(16) ushort_t xsT[64 * 72];   // [p][t^sw]  t-contig
    __shared__ __align__(16) ushort_t BwT[64 * 72];   // [n][t^sw]  t-contig, weighted by wc[t]
    __shared__ float wc[64];
    const int tid = threadIdx.x;
    const int ts = tid >> 2, q4 = (tid & 3) * 16;
    const int l = c * QCH + ts;
    const int tswz = ts ^ ((tid & 3) << 4);           // sw = (p>>4)<<4, p-group = tid&3
    if (tid < 64) {
        size_t gl = (size_t)h * MROWS + (size_t)b * SEQ + c * QCH + tid;   // [head][row] planes
        float v = dalog[gl];
#pragma unroll
        for (int off = 1; off < 64; off <<= 1) {
            float u = __shfl_up(v, off, 64);
            if (tid >= off) v += u;
        }
        float tot = __shfl(v, 63, 64);
        wc[tid] = __expf(tot - v) * dtv[gl];
        if (tid == 63) cdecay[(c * BATCH + b) * NHEADS + h] = __expf(tot);
    }
    { // x: load precomputed conv+silu xs slice, transposed store (swizzled)
        const int ch0 = h * HEADDIM + q4;
        const ushort_t* rp = xs + ((size_t)b * SEQ + l) * 1024 + ch0;
        union { uint4 u; ushort_t s[8]; } u0, u1;
        u0.u = *(const uint4*)rp; u1.u = *(const uint4*)(rp + 8);
#pragma unroll
        for (int i = 0; i < 8; i++) {
            xsT[(q4 + i) * 72 + tswz]     = u0.s[i];
            xsT[(q4 + 8 + i) * 72 + tswz] = u1.s[i];
        }
    }
    __syncthreads();
    { // B: load precomputed, weight by wc[t], transposed store (swizzled)
        float bv[16];
        const ushort_t* rp = bcc + ((size_t)b * SEQ + l) * 128;
        bf8_to_f(rp + q4, bv); bf8_to_f(rp + q4 + 8, bv + 8);
        const float wt = wc[ts];
#pragma unroll
        for (int i = 0; i < 16; i++) BwT[(q4 + i) * 72 + tswz] = f2bfu(bv[i] * wt);
    }
    __syncthreads();
    const int wave = tid >> 6, lane = tid & 63;
    const int quad = lane >> 4, l16 = lane & 15;
    f32x4 acc[4];
#pragma unroll
    for (int j = 0; j < 4; j++) acc[j] = (f32x4){0.f, 0.f, 0.f, 0.f};
#pragma unroll
    for (int kk = 0; kk < 64; kk += 32) {
        bf16x8 af = *(const bf16x8*)(&xsT[(wave * 16 + l16) * 72 + ((kk + quad * 8) ^ ((wave & 3) << 4))]);
#pragma unroll
        for (int j = 0; j < 4; j++) {
            bf16x8 bf_ = *(const bf16x8*)(&BwT[(j * 16 + l16) * 72 + ((kk + quad * 8) ^ ((j & 3) << 4))]);
            acc[j] = __builtin_amdgcn_mfma_f32_16x16x32_bf16(af, bf_, acc[j], 0, 0, 0);
        }
    }
    ushort_t* base = statesT + ((size_t)(c * BATCH + b) * NHEADS + h) * (HEADDIM * DSTATE);
#pragma unroll
    for (int j = 0; j < 4; j++)
#pragma unroll
        for (int r = 0; r < 4; r++)
            base[(wave * 16 + quad * 4 + r) * 64 + j * 16 + l16] = f2bfu(acc[j][r]);
}

// ---------------------------------------------------------------- sequential chunk combine (256 blocks x 128 thr)
__global__ void scan_combine_k(ushort_t* __restrict__ states, const float* __restrict__ cdecay)
{
    const int blk = blockIdx.x;           // 256 = 2*16*8
    const int eighth = blk & 7;
    const int h = (blk >> 3) & 15;
    const int b = blk >> 7;
    const int tid = threadIdx.x;          // 128
    __shared__ float dec[64];
    if (tid < 64) dec[tid] = cdecay[(tid * BATCH + b) * NHEADS + h];
    __syncthreads();
    const size_t cstride = (size_t)BATCH * NHEADS * HEADDIM * DSTATE;  // elements
    ushort_t* base = states + ((size_t)b * NHEADS + h) * (HEADDIM * DSTATE) + eighth * 512 + tid * 4;
    float sx = 0.f, sy = 0.f, sz = 0.f, sw = 0.f;
    uint2 pre[4];
#pragma unroll
    for (int j = 0; j < 4; j++) pre[j] = *(const uint2*)(base + j * cstride);
    for (int c = 0; c < NCHUNK; c++) {
        uint2 Sc = pre[c & 3];
        if (c + 4 < NCHUNK) pre[c & 3] = *(const uint2*)(base + (size_t)(c + 4) * cstride);
        float d = dec[c];
        uint2 o;
        o.x = (uint_t)f2bfu(sx) | ((uint_t)f2bfu(sy) << 16);
        o.y = (uint_t)f2bfu(sz) | ((uint_t)f2bfu(sw) << 16);
        *(uint2*)(base + (size_t)c * cstride) = o;
        sx = d * sx + __uint_as_float((Sc.x & 0xFFFFu) << 16);
        sy = d * sy + __uint_as_float(Sc.x & 0xFFFF0000u);
        sz = d * sz + __uint_as_float((Sc.y & 0xFFFFu) << 16);
        sw = d * sw + __uint_as_float(Sc.y & 0xFFFF0000u);
    }
}

// ---------------------------------------------------------------- per-chunk y (MFMA): att + intra + inter + D + gate
// Barrier schedule (wave-locality derived): attL rows are wave-local; only
// the BLb overwrite needs a barrier; gate rows are wave-local.
__global__ __launch_bounds__(256, 3)
void chunk_y_k(const ushort_t* __restrict__ xs, const ushort_t* __restrict__ bcc,
               ushort_t* zio,
               const float* __restrict__ dtv, const float* __restrict__ dalog,
               const ushort_t* __restrict__ statesT, const float* __restrict__ Dp)
{
    const int c = blockIdx.x, h = blockIdx.y, b = blockIdx.z;
    __shared__ __align__(16) ushort_t CLb [64 * 72];  // C[t][n] n-contig
    __shared__ __align__(16) ushort_t BLb [64 * 72];  // B[s][n] n-contig -> ybuf[t][p]
    __shared__ __align__(16) ushort_t xsT [64 * 72];  // xs^T [p][t^sw] t-contig (swizzled)
    __shared__ __align__(16) ushort_t attL[64 * 72];  // att[t][s] s-contig
    __shared__ float cum[64], wdt[64];
    const int tid = threadIdx.x;
    const int ts = tid >> 2, q4 = (tid & 3) * 16;
    const int l = c * QCH + ts;
    const int tswz = ts ^ ((tid & 3) << 4);
    const float Dh = Dp[h];
    { // x: load precomputed conv+silu xs slice, transposed store (swizzled)
        const int ch0 = h * HEADDIM + q4;
        const ushort_t* rp = xs + ((size_t)b * SEQ + l) * 1024 + ch0;
        union { uint4 u; ushort_t s[8]; } u0, u1;
        u0.u = *(const uint4*)rp; u1.u = *(const uint4*)(rp + 8);
#pragma unroll
        for (int i = 0; i < 8; i++) {
            xsT[(q4 + i) * 72 + tswz]     = u0.s[i];
            xsT[(q4 + 8 + i) * 72 + tswz] = u1.s[i];
        }
    }
    { // B, C: plain copies from precomputed bcc
        const ushort_t* rp = bcc + ((size_t)b * SEQ + l) * 128;
        *(uint4*)&BLb[ts * 72 + q4]     = *(const uint4*)(rp + q4);
        *(uint4*)&BLb[ts * 72 + q4 + 8] = *(const uint4*)(rp + q4 + 8);
        *(uint4*)&CLb[ts * 72 + q4]     = *(const uint4*)(rp + 64 + q4);
        *(uint4*)&CLb[ts * 72 + q4 + 8] = *(const uint4*)(rp + 64 + q4 + 8);
    }
    if (tid < 64) {
        size_t gl = (size_t)h * MROWS + (size_t)b * SEQ + c * QCH + tid;   // [head][row] planes
        float v = dalog[gl];
#pragma unroll
        for (int off = 1; off < 64; off <<= 1) {
            float u = __shfl_up(v, off, 64);
            if (tid >= off) v += u;
        }
        cum[tid] = v;
        wdt[tid] = dtv[gl];
    }
    __syncthreads();
    const int wave = tid >> 6, lane = tid & 63;
    const int quad = lane >> 4, l16 = lane & 15;
    {
        f32x4 sacc[4];
#pragma unroll
        for (int j = 0; j < 4; j++) sacc[j] = (f32x4){0.f, 0.f, 0.f, 0.f};
#pragma unroll
        for (int kk = 0; kk < 64; kk += 32) {
            bf16x8 af = *(const bf16x8*)(&CLb[(wave * 16 + l16) * 72 + kk + quad * 8]);
#pragma unroll
            for (int j = 0; j < 4; j++) {
                bf16x8 bf_ = *(const bf16x8*)(&BLb[(j * 16 + l16) * 72 + kk + quad * 8]);
                sacc[j] = __builtin_amdgcn_mfma_f32_16x16x32_bf16(af, bf_, sacc[j], 0, 0, 0);
            }
        }
#pragma unroll
        for (int r = 0; r < 4; r++) {
            const int t = wave * 16 + quad * 4 + r;
            const float ct = cum[t];
#pragma unroll
            for (int j = 0; j < 4; j++) {
                const int s = j * 16 + l16;
                float a = (s <= t) ? sacc[j][r] * __expf(ct - cum[s]) * wdt[s] : 0.f;
                attL[t * 72 + s] = f2bfu(a);
            }
        }
    }
    // no barrier: attL rows are wave-local; Y/I MFMA starts immediately
    {
        f32x4 accY[4], accI[4];
#pragma unroll
        for (int j = 0; j < 4; j++) { accY[j] = (f32x4){0.f, 0.f, 0.f, 0.f}; accI[j] = (f32x4){0.f, 0.f, 0.f, 0.f}; }
        const ushort_t* spg = statesT + ((size_t)(c * BATCH + b) * NHEADS + h) * (HEADDIM * DSTATE);
#pragma unroll
        for (int kk = 0; kk < 64; kk += 32) {
            bf16x8 a2 = *(const bf16x8*)(&attL[(wave * 16 + l16) * 72 + kk + quad * 8]);
            bf16x8 a3 = *(const bf16x8*)(&CLb [(wave * 16 + l16) * 72 + kk + quad * 8]);
#pragma unroll
            for (int j = 0; j < 4; j++) {
                bf16x8 b2 = *(const bf16x8*)(&xsT[(j * 16 + l16) * 72 + ((kk + quad * 8) ^ ((j & 3) << 4))]);
                accY[j] = __builtin_amdgcn_mfma_f32_16x16x32_bf16(a2, b2, accY[j], 0, 0, 0);
                bf16x8 b3 = *(const bf16x8*)(spg + (j * 16 + l16) * 64 + kk + quad * 8);
                accI[j] = __builtin_amdgcn_mfma_f32_16x16x32_bf16(a3, b3, accI[j], 0, 0, 0);
            }
        }
        __syncthreads();   // all waves done reading BLb (att B-operand) before overwrite
#pragma unroll
        for (int r = 0; r < 4; r++) {
            const int t = wave * 16 + quad * 4 + r;
            const float et = __expf(cum[t]);
#pragma unroll
            for (int j = 0; j < 4; j++) {
                const int p = j * 16 + l16;
                float xv = bf2f(xsT[p * 72 + (t ^ ((j & 3) << 4))]);
                float y = accY[j][r] + et * accI[j][r] + Dh * xv;
                BLb[t * 72 + p] = f2bfu(y);
            }
        }
    }
    // no barrier: BLb y-rows [16w,16w+16) are wave-local to the gate below
    {
        ushort_t* zrow = zio + ((size_t)b * SEQ + l) * DINNER + h * HEADDIM + q4;
        float zv[16], yv[16], o[16];
        bf8_to_f(zrow, zv); bf8_to_f(zrow + 8, zv + 8);
        bf8_to_f(&BLb[ts * 72 + q4], yv); bf8_to_f(&BLb[ts * 72 + q4 + 8], yv + 8);
#pragma unroll
        for (int j = 0; j < 16; j++) {
            float z = zv[j];
            o[j] = yv[j] * z * sigmoidf_(z);
        }
        *(uint4*)(zrow)     = f8_to_bf(o);
        *(uint4*)(zrow + 8) = f8_to_bf(o + 8);
    }
}

// ---------------------------------------------------------------- launch
extern "C" void kernel_launch(void* const* d_in, const int* in_sizes, int n_in,
                              void* d_out, int out_size, void* d_ws, size_t ws_size,
                              hipStream_t stream)
{
    const float* x      = (const float*)d_in[0];
    const float* W_in   = (const float*)d_in[1];
    const float* conv_w = (const float*)d_in[2];
    const float* conv_b = (const float*)d_in[3];
    const float* dt_b   = (const float*)d_in[4];
    const float* A_log  = (const float*)d_in[5];
    const float* Dp     = (const float*)d_in[6];
    const float* nw     = (const float*)d_in[7];
    const float* W_out  = (const float*)d_in[8];
    float* out = (float*)d_out;                    // (2,4096,512) fp32

    // ---- workspace (48 MiB high-water) ----
    // [0,16M): zbuf (z -> gated y, in place)
    // [16M,32M): xs (post-conv+silu x) — rows>=3/tile by gemm0, rows<3 by conv_k fixup
    // [32M, 32M+0.75M): xbnd (raw pre-conv boundary rows; dead after conv_k) -> statesT
    char* w = (char*)d_ws;
    ushort_t* zbuf    = (ushort_t*)(w);
    ushort_t* xs      = (ushort_t*)(w + 16777216);
    ushort_t* xbnd    = (ushort_t*)(w + 33554432);
    ushort_t* statesT = (ushort_t*)(w + 33554432);  // overwrites dead xbnd
    // ---- d_out (16.78 MB fp32) doubles as scratch until GEMM2 overwrites it ----
    char* dscr = (char*)d_out;
    ushort_t* xpbc  = (ushort_t*)(dscr);                // [0, 2M): pre-conv B|C
    float*    dtv   = (float*)(dscr + 2097152);         // [2M, 2.5M): [head][row] planes
    float*    dalog = (float*)(dscr + 2621440);         // [2.5M, 3M): [head][row] planes
    float*    cdec  = (float*)(dscr + 3145728);         // [3M, 3M+16K)
    ushort_t* WinT  = (ushort_t*)(dscr + 4194304);      // [4M, 6.25M): W_in^T padded (dead after gemm0)
    ushort_t* bcc   = (ushort_t*)(dscr + 4194304);      // [4M, 6M): post-conv B|C (after gemm0)
    ushort_t* WoutT = (ushort_t*)(dscr + 6815744);      // [6.5M, 7.5M): W_out^T*nw (survives to gemm1)
    ushort_t* xb    = (ushort_t*)(dscr + 8388608);      // [8M, 16M): x bf16 (dead before gemm2)

    // prep: cast x + W_in^T + W_out^T*nw, one launch (blocks co-schedule)
    prep_k<<<2048 + (NPROJ_PAD / 32) * (DMODEL / 32) + (DMODEL / 32) * (DINNER / 32), 256, 0, stream>>>(
        x, xb, W_in, WinT, W_out, WoutT, nw);
    gemm_k<0><<<dim3(NPROJ_PAD / 128, MROWS / 128), 256, 0, stream>>>(
        xb, WinT, zbuf, xs, xbnd, xpbc, dtv, dalog, dt_b, A_log, conv_w, conv_b,
        nullptr, MROWS, NPROJ, DMODEL);
    // WinT dead; bcc overwrites its region. conv: B/C conv + x boundary fixup
    conv_k<<<512 + 96, 256, 0, stream>>>(xpbc, xbnd, conv_w, conv_b, bcc, xs);
    // xbnd dead; statesT overwrites its region
    chunk_state_k<<<dim3(NCHUNK, NHEADS, BATCH), 256, 0, stream>>>(
        xs, bcc, dtv, dalog, statesT, cdec);
    scan_combine_k<<<BATCH * NHEADS * 8, 128, 0, stream>>>(statesT, cdec);
    chunk_y_k<<<dim3(NCHUNK, NHEADS, BATCH), 256, 0, stream>>>(
        xs, bcc, zbuf, dtv, dalog, statesT, Dp);
    // RMSNorm fused into gemm_k<1>
    gemm_k<1><<<dim3(DMODEL / 64, MROWS / 128), 256, 0, stream>>>(
        zbuf, WoutT, nullptr, nullptr, nullptr, nullptr, nullptr, nullptr,
        nullptr, nullptr, nullptr, nullptr, out, MROWS, DMODEL, DINNER);
}

// Round 10
// 205.327 us; speedup vs baseline: 1.0119x; 1.0119x over previous
//
#include <hip/hip_runtime.h>
#include <hip/hip_bf16.h>

#define BATCH   2
#define SEQ     4096
#define DMODEL  512
#define DINNER  1024
#define DSTATE  64
#define NHEADS  16
#define HEADDIM 64
#define CONVDIM 1152
#define NPROJ   2192
#define NPROJ_PAD 2304        // 18*128 — exact tile grid for gemm0
#define MROWS   (BATCH*SEQ)   // 8192
#define QCH     64
#define NCHUNK  (SEQ/QCH)     // 64 chunks per batch

typedef short bf16x8 __attribute__((ext_vector_type(8)));
typedef float f32x4  __attribute__((ext_vector_type(4)));
using bf16 = __hip_bfloat16;
typedef unsigned short ushort_t;
typedef unsigned int   uint_t;

__device__ __forceinline__ float sigmoidf_(float x) { return 1.f / (1.f + __expf(-x)); }
__device__ __forceinline__ float bf2f(ushort_t u) { return __uint_as_float((uint_t)u << 16); }
__device__ __forceinline__ ushort_t f2bfu(float f) {
    bf16 h = __float2bfloat16(f);
    return *(ushort_t*)&h;
}
__device__ __forceinline__ void bf8_to_f(const ushort_t* __restrict__ p, float* __restrict__ f) {
    uint4 u = *(const uint4*)p;
    f[0] = __uint_as_float((u.x & 0xFFFFu) << 16);
    f[1] = __uint_as_float(u.x & 0xFFFF0000u);
    f[2] = __uint_as_float((u.y & 0xFFFFu) << 16);
    f[3] = __uint_as_float(u.y & 0xFFFF0000u);
    f[4] = __uint_as_float((u.z & 0xFFFFu) << 16);
    f[5] = __uint_as_float(u.z & 0xFFFF0000u);
    f[6] = __uint_as_float((u.w & 0xFFFFu) << 16);
    f[7] = __uint_as_float(u.w & 0xFFFF0000u);
}
__device__ __forceinline__ uint4 f8_to_bf(const float* __restrict__ f) {
    union { ushort_t s[8]; uint4 u; } r;
#pragma unroll
    for (int i = 0; i < 8; i++) r.s[i] = f2bfu(f[i]);
    return r.u;
}

// async global->LDS, 16B per lane; lds dest is wave-uniform base + lane*16
__device__ __forceinline__ void gload_lds16(const ushort_t* g, ushort_t* l)
{
    __builtin_amdgcn_global_load_lds(
        (const __attribute__((address_space(1))) void*)g,
        (__attribute__((address_space(3)))       void*)l,
        16, 0, 0);
}

// ---------------------------------------------------------------- merged prep: cast x + transpose W_in + transpose W_out
// blocks [0,2048): cast fp32->bf16, 8 elems/thread
// blocks [2048,3200): W_in^T (512x2192 -> 2304x512, zero-pad)
// blocks [3200,3712): W_out^T scaled by norm_weight (1024x512 -> 512x1024)
__global__ __launch_bounds__(256, 4)
void prep_k(const float* __restrict__ x, ushort_t* __restrict__ xb,
            const float* __restrict__ W_in, ushort_t* __restrict__ WinT,
            const float* __restrict__ W_out, ushort_t* __restrict__ WoutT,
            const float* __restrict__ nw)
{
    __shared__ __align__(16) ushort_t tile[32][33];
    const int bid = blockIdx.x, tid = threadIdx.x;
    if (bid < 2048) {
        int i = bid * 256 + tid;                    // n8 = 524288 exactly
        float f[8];
        *(float4*)(f + 0) = ((const float4*)x)[i * 2 + 0];
        *(float4*)(f + 4) = ((const float4*)x)[i * 2 + 1];
        ((uint4*)xb)[i] = f8_to_bf(f);
        return;
    }
    const int tx = tid & 31, ty = tid >> 5;         // 32 x 8
    const float* in; ushort_t* out; int R, C, Cpad; const float* sv;
    int bx, by;
    if (bid < 3200) {
        int b2 = bid - 2048;                        // grid (72, 16)
        bx = b2 % (NPROJ_PAD / 32); by = b2 / (NPROJ_PAD / 32);
        in = W_in; out = WinT; R = DMODEL; C = NPROJ; Cpad = NPROJ_PAD; sv = nullptr;
    } else {
        int b3 = bid - 3200;                        // grid (16, 32)
        bx = b3 % (DMODEL / 32); by = b3 / (DMODEL / 32);
        in = W_out; out = WoutT; R = DINNER; C = DMODEL; Cpad = DMODEL; sv = nw;
    }
    int c0 = bx * 32, r0 = by * 32;
#pragma unroll
    for (int i = 0; i < 32; i += 8) {
        int r = r0 + ty + i, c = c0 + tx;
        float v = (r < R && c < C) ? in[(size_t)r * C + c] : 0.f;
        if (sv && r < R) v *= sv[r];
        tile[ty + i][tx] = f2bfu(v);
    }
    __syncthreads();
#pragma unroll
    for (int i = 0; i < 32; i += 8) {
        int orow = c0 + ty + i, ocol = r0 + tx;
        if (orow < Cpad && ocol < R) out[(size_t)orow * R + ocol] = tile[tx][ty + i];
    }
}

// ---------------------------------------------------------------- merged conv: B/C conv+SiLU  +  x conv+SiLU (sliding window)
// blocks [0,512): bcconv; blocks [512,768): xconv
__global__ __launch_bounds__(256, 4)
void conv_k(const ushort_t* __restrict__ xpbc, const ushort_t* __restrict__ xpre,
            const float* __restrict__ cw, const float* __restrict__ cb,
            ushort_t* __restrict__ bcc, ushort_t* __restrict__ xs)
{
    const int bid = blockIdx.x, tid = threadIdx.x;
    if (bid < 512) {
        int idx = bid * 256 + tid;                   // MROWS*16
        int row = idx >> 4, c8 = (idx & 15) * 8;
        int l = row & (SEQ - 1);
        float acc[8];
#pragma unroll
        for (int i = 0; i < 8; i++) acc[i] = cb[1024 + c8 + i];
#pragma unroll
        for (int j = 0; j < 4; j++) {
            int ll = l - 3 + j;
            if (ll >= 0) {
                float v[8];
                bf8_to_f(xpbc + (size_t)(row - 3 + j) * 128 + c8, v);
#pragma unroll
                for (int i = 0; i < 8; i++) acc[i] += cw[(1024 + c8 + i) * 4 + j] * v[i];
            }
        }
#pragma unroll
        for (int i = 0; i < 8; i++) { float v = acc[i]; acc[i] = v * sigmoidf_(v); }
        *(uint4*)(bcc + (size_t)row * 128 + c8) = f8_to_bf(acc);
        return;
    }
    // xconv: sliding-window, reads each xpre row once
    const int b2 = bid - 512;                        // grid (128, 2) flattened
    const int gx = b2 & 127, b = b2 >> 7;
    const int c8 = (tid & 127) * 8;
    const int rh = tid >> 7;                         // 0/1
    const int l0 = gx * 32 + rh * 16;
    float w[4][8], cbv[8];
#pragma unroll
    for (int i = 0; i < 8; i++) {
        cbv[i] = cb[c8 + i];
        float4 wv = *(const float4*)(cw + (size_t)(c8 + i) * 4);
        w[0][i] = wv.x; w[1][i] = wv.y; w[2][i] = wv.z; w[3][i] = wv.w;
    }
    float win[3][8];
#pragma unroll
    for (int j = 0; j < 3; j++) {
        int ll = l0 - 3 + j;
        if (ll >= 0) bf8_to_f(xpre + ((size_t)b * SEQ + ll) * 1024 + c8, win[j]);
        else {
#pragma unroll
            for (int i = 0; i < 8; i++) win[j][i] = 0.f;
        }
    }
#pragma unroll 4
    for (int r = 0; r < 16; r++) {
        int l = l0 + r;
        float cur[8], o[8];
        bf8_to_f(xpre + ((size_t)b * SEQ + l) * 1024 + c8, cur);
#pragma unroll
        for (int i = 0; i < 8; i++) {
            float a = cbv[i] + w[0][i] * win[0][i] + w[1][i] * win[1][i]
                             + w[2][i] * win[2][i] + w[3][i] * cur[i];
            o[i] = a * sigmoidf_(a);
        }
        *(uint4*)(xs + ((size_t)b * SEQ + l) * 1024 + c8) = f8_to_bf(o);
#pragma unroll
        for (int i = 0; i < 8; i++) { win[0][i] = win[1][i]; win[1][i] = win[2][i]; win[2][i] = cur[i]; }
    }
}

// ---------------------------------------------------------------- GEMM (bf16 MFMA), m97 structure + XCD swizzle.
// [R9 conv-fusion REVERTED: fused epilogue cost +6us on gemm0 vs −4 in conv_k.
//  R7 8-phase REVERTED earlier: T3+T4 without T2 = 16-way ds_read conflicts +
//  1 block/CU. Known residual: 7.08e6 SQ_LDS_BANK_CONFLICT from linear LDS
//  fragment reads — pre-swizzle fix is measured NULL on 2-phase (m230/m252).]
// MODE 0: in-proj (TN=128, split outputs + dt/dalog [head][row] planes);
//         launch_bounds min-waves 4 -> 4 blocks/CU (LDS 33.8KB x4 = 135KB ok).
// MODE 1: out-proj (TN=64) with FUSED RMSNorm (row ssq from A-fragments;
//         nw folded into Bt).
template<int MODE>
__global__ __launch_bounds__(256, 4)
void gemm_k(const ushort_t* __restrict__ A, const ushort_t* __restrict__ Bt,
            ushort_t* __restrict__ zbuf, ushort_t* __restrict__ xpx,
            ushort_t* __restrict__ xpbc, float* __restrict__ dtv,
            float* __restrict__ dalog, const float* __restrict__ dt_b,
            const float* __restrict__ A_log, float* __restrict__ outf,
            int M, int N, int K)
{
    constexpr int TN = (MODE == 1) ? 64 : 128;   // block n-extent
    constexpr int NJ = TN / 32;                  // n-frags per wave (2 or 4)
    constexpr int SC = 132;
    constexpr int SMEM_ELTS = (MODE == 1) ? (128 * 64 + TN * 64) : (128 * SC);
    __shared__ __align__(16) ushort_t smem[SMEM_ELTS];
    ushort_t* As = smem;
    ushort_t* Bs = smem + 128 * 64;
    ushort_t* Cs = smem;

    const int tid  = threadIdx.x;
    const int wave = tid >> 6, lane = tid & 63;
    const int quad = lane >> 4, l16 = lane & 15;
    const int wm = (wave >> 1) * 64, wn = (wave & 1) * (TN / 2);

    // XCD-aware swizzle (nwg % 8 == 0 for both modes -> bijective)
    const int GX = gridDim.x;
    int lin = blockIdx.y * GX + blockIdx.x;
    const int cpx = (GX * gridDim.y) >> 3;
    lin = (lin & 7) * cpx + (lin >> 3);
    const int m0 = (lin / GX) * 128, n0 = (lin % GX) * TN;

    // staging: each gload_lds16 writes 1KB of LDS = 8 rows x 64 bf16 (lane l -> row l/8, elems (l&7)*8)
    const int srow = lane >> 3;          // 0..7
    const int scol = (lane & 7) * 8;     // 0,8,..,56
    const ushort_t* ag = A  + (size_t)(m0 + wave * 32       + srow) * K + scol;
    const ushort_t* bg = Bt + (size_t)(n0 + wave * (TN / 4) + srow) * K + scol;
    ushort_t* al = As + wave * 32 * 64;
    ushort_t* bl = Bs + wave * (TN / 4) * 64;

    f32x4 acc[4][NJ];
#pragma unroll
    for (int i = 0; i < 4; i++)
#pragma unroll
        for (int j = 0; j < NJ; j++) acc[i][j] = (f32x4){0.f, 0.f, 0.f, 0.f};
    float ssq4[4] = {0.f, 0.f, 0.f, 0.f};   // MODE 1: row sum-of-squares partials

    for (int k0 = 0; k0 < K; k0 += 64) {
        __syncthreads();                       // previous compute done before overwrite
#pragma unroll
        for (int j = 0; j < 4; j++)
            gload_lds16(ag + (size_t)(j * 8) * K + k0, al + j * 8 * 64);
#pragma unroll
        for (int j = 0; j < NJ; j++)
            gload_lds16(bg + (size_t)(j * 8) * K + k0, bl + j * 8 * 64);
        __syncthreads();                       // vmcnt(0) drained here -> tile ready
#pragma unroll
        for (int kk = 0; kk < 64; kk += 32) {
            bf16x8 af[4], bfr[NJ];
#pragma unroll
            for (int i = 0; i < 4; i++)
                af[i] = *(const bf16x8*)(&As[(wm + i * 16 + l16) * 64 + kk + quad * 8]);
#pragma unroll
            for (int j = 0; j < NJ; j++)
                bfr[j] = *(const bf16x8*)(&Bs[(wn + j * 16 + l16) * 64 + kk + quad * 8]);
#pragma unroll
            for (int i = 0; i < 4; i++)
#pragma unroll
                for (int j = 0; j < NJ; j++)
                    acc[i][j] = __builtin_amdgcn_mfma_f32_16x16x32_bf16(af[i], bfr[j], acc[i][j], 0, 0, 0);
            if (MODE == 1 && (wave & 1) == 0) {
#pragma unroll
                for (int i = 0; i < 4; i++)
#pragma unroll
                    for (int e = 0; e < 8; e++) {
                        float f = bf2f((ushort_t)af[i][e]);
                        ssq4[i] += f * f;
                    }
            }
        }
    }
    if (MODE == 1) {
        __syncthreads();                       // all LDS reads done; smem reused for row scales
        float* smemf = (float*)smem;
        if ((wave & 1) == 0) {
#pragma unroll
            for (int i = 0; i < 4; i++) {
                float s = ssq4[i];
                s += __shfl_xor(s, 16, 64);    // reduce over quads (cols)
                s += __shfl_xor(s, 32, 64);
                if (quad == 0) smemf[wm + i * 16 + l16] = s;
            }
        }
        __syncthreads();
#pragma unroll
        for (int i = 0; i < 4; i++)
#pragma unroll
            for (int j = 0; j < NJ; j++) {
                int col  = n0 + wn + j * 16 + l16;
                int rowl = wm + i * 16 + quad * 4;
#pragma unroll
                for (int r = 0; r < 4; r++) {
                    float sc = rsqrtf(smemf[rowl + r] * (1.f / DINNER) + 1e-5f);
                    outf[(size_t)(m0 + rowl + r) * N + col] = acc[i][j][r] * sc;
                }
            }
    } else if (n0 == 2176) {
        // dt head-block: dtv/dalog stored as [head][row] planes -> 16B-contiguous writes
#pragma unroll
        for (int i = 0; i < 4; i++)
#pragma unroll
            for (int j = 0; j < NJ; j++) {
                int col = n0 + wn + j * 16 + l16;
                int rowb = m0 + wm + i * 16 + quad * 4;
                if (col < N) {
                    int hh = col - 2176;
#pragma unroll
                    for (int r = 0; r < 4; r++) {
                        float v = acc[i][j][r];
                        size_t g = (size_t)hh * MROWS + (rowb + r);
                        float raw = v + dt_b[hh];
                        float sp  = (raw > 20.f) ? raw : log1pf(__expf(raw));
                        dtv  [g] = sp;
                        dalog[g] = -__expf(A_log[hh]) * sp;
                    }
                }
            }
    } else {
        __syncthreads();                       // all fragment reads done before Cs overlays As/Bs
#pragma unroll
        for (int i = 0; i < 4; i++)
#pragma unroll
            for (int j = 0; j < NJ; j++)
#pragma unroll
                for (int r = 0; r < 4; r++)
                    Cs[(wm + i * 16 + quad * 4 + r) * SC + wn + j * 16 + l16] = f2bfu(acc[i][j][r]);
        __syncthreads();
        ushort_t* dst; int ld, coff;
        if (n0 < 1024)      { dst = zbuf; ld = 1024; coff = n0; }
        else if (n0 < 2048) { dst = xpx;  ld = 1024; coff = n0 - 1024; }
        else                { dst = xpbc; ld = 128;  coff = 0; }
#pragma unroll
        for (int jj = 0; jj < 8; jj++) {
            int idx = jj * 256 + tid;
            int row = idx >> 4, cq = (idx & 15) * 8;
            uint4 v = *(const uint4*)&Cs[row * SC + cq];
            *(uint4*)&dst[(size_t)(m0 + row) * ld + coff + cq] = v;
        }
    }
}

// ---------------------------------------------------------------- per-chunk state outer product (MFMA)
// Transposed LDS tiles use col-XOR swizzle t' = t ^ ((p>>4)<<4): the 4 quad-
// groups of a wave land in 4 disjoint 32B windows. Read side: (p>>4) is
// uniform per fragment instruction and the XOR is 32B-granular, so
// ds_read_b128 stays aligned.
__global__ __launch_bounds__(256, 3)
void chunk_state_k(const ushort_t* __restrict__ xs, const ushort_t* __restrict__ bcc,
                   const float* __restrict__ dtv, const float* __restrict__ dalog,
                   ushort_t* __restrict__ statesT, float* __restrict__ cdecay)
{
    const int c = blockIdx.x, h = blockIdx.y, b = blockIdx.z;
    __shared__ __align__(16) ushort_t xsT[64 * 72];   // [p][t^sw]  t-contig
    __shared__ __align__(16) ushort_t BwT[64 * 72];   // [n][t^sw]  t-contig, weighted by wc[t]
    __shared__ float wc[64];
    const int tid = threadIdx.x;
    const int ts = tid >> 2, q4 = (tid & 3) * 16;
    const int l = c * QCH + ts;
    const int tswz = ts ^ ((tid & 3) << 4);           // sw = (p>>4)<<4, p-group = tid&3
    if (tid < 64) {
        size_t gl = (size_t)h * MROWS + (size_t)b * SEQ + c * QCH + tid;   // [head][row] planes
        float v = dalog[gl];
#pragma unroll
        for (int off = 1; off < 64; off <<= 1) {
            float u = __shfl_up(v, off, 64);
            if (tid >= off) v += u;
        }
        float tot = __shfl(v, 63, 64);
        wc[tid] = __expf(tot - v) * dtv[gl];
        if (tid == 63) cdecay[(c * BATCH + b) * NHEADS + h] = __expf(tot);
    }
    { // x: load precomputed conv+silu xs slice, transposed store (swizzled)
        const int ch0 = h * HEADDIM + q4;
        const ushort_t* rp = xs + ((size_t)b * SEQ + l) * 1024 + ch0;
        union { uint4 u; ushort_t s[8]; } u0, u1;
        u0.u = *(const uint4*)rp; u1.u = *(const uint4*)(rp + 8);
#pragma unroll
        for (int i = 0; i < 8; i++) {
            xsT[(q4 + i) * 72 + tswz]     = u0.s[i];
            xsT[(q4 + 8 + i) * 72 + tswz] = u1.s[i];
        }
    }
    __syncthreads();
    { // B: load precomputed, weight by wc[t], transposed store (swizzled)
        float bv[16];
        const ushort_t* rp = bcc + ((size_t)b * SEQ + l) * 128;
        bf8_to_f(rp + q4, bv); bf8_to_f(rp + q4 + 8, bv + 8);
        const float wt = wc[ts];
#pragma unroll
        for (int i = 0; i < 16; i++) BwT[(q4 + i) * 72 + tswz] = f2bfu(bv[i] * wt);
    }
    __syncthreads();
    const int wave = tid >> 6, lane = tid & 63;
    const int quad = lane >> 4, l16 = lane & 15;
    f32x4 acc[4];
#pragma unroll
    for (int j = 0; j < 4; j++) acc[j] = (f32x4){0.f, 0.f, 0.f, 0.f};
#pragma unroll
    for (int kk = 0; kk < 64; kk += 32) {
        bf16x8 af = *(const bf16x8*)(&xsT[(wave * 16 + l16) * 72 + ((kk + quad * 8) ^ ((wave & 3) << 4))]);
#pragma unroll
        for (int j = 0; j < 4; j++) {
            bf16x8 bf_ = *(const bf16x8*)(&BwT[(j * 16 + l16) * 72 + ((kk + quad * 8) ^ ((j & 3) << 4))]);
            acc[j] = __builtin_amdgcn_mfma_f32_16x16x32_bf16(af, bf_, acc[j], 0, 0, 0);
        }
    }
    ushort_t* base = statesT + ((size_t)(c * BATCH + b) * NHEADS + h) * (HEADDIM * DSTATE);
#pragma unroll
    for (int j = 0; j < 4; j++)
#pragma unroll
        for (int r = 0; r < 4; r++)
            base[(wave * 16 + quad * 4 + r) * 64 + j * 16 + l16] = f2bfu(acc[j][r]);
}

// ---------------------------------------------------------------- sequential chunk combine (256 blocks x 128 thr)
__global__ void scan_combine_k(ushort_t* __restrict__ states, const float* __restrict__ cdecay)
{
    const int blk = blockIdx.x;           // 256 = 2*16*8
    const int eighth = blk & 7;
    const int h = (blk >> 3) & 15;
    const int b = blk >> 7;
    const int tid = threadIdx.x;          // 128
    __shared__ float dec[64];
    if (tid < 64) dec[tid] = cdecay[(tid * BATCH + b) * NHEADS + h];
    __syncthreads();
    const size_t cstride = (size_t)BATCH * NHEADS * HEADDIM * DSTATE;  // elements
    ushort_t* base = states + ((size_t)b * NHEADS + h) * (HEADDIM * DSTATE) + eighth * 512 + tid * 4;
    float sx = 0.f, sy = 0.f, sz = 0.f, sw = 0.f;
    uint2 pre[4];
#pragma unroll
    for (int j = 0; j < 4; j++) pre[j] = *(const uint2*)(base + j * cstride);
    for (int c = 0; c < NCHUNK; c++) {
        uint2 Sc = pre[c & 3];
        if (c + 4 < NCHUNK) pre[c & 3] = *(const uint2*)(base + (size_t)(c + 4) * cstride);
        float d = dec[c];
        uint2 o;
        o.x = (uint_t)f2bfu(sx) | ((uint_t)f2bfu(sy) << 16);
        o.y = (uint_t)f2bfu(sz) | ((uint_t)f2bfu(sw) << 16);
        *(uint2*)(base + (size_t)c * cstride) = o;
        sx = d * sx + __uint_as_float((Sc.x & 0xFFFFu) << 16);
        sy = d * sy + __uint_as_float(Sc.x & 0xFFFF0000u);
        sz = d * sz + __uint_as_float((Sc.y & 0xFFFFu) << 16);
        sw = d * sw + __uint_as_float(Sc.y & 0xFFFF0000u);
    }
}

// ---------------------------------------------------------------- per-chunk y (MFMA): att + intra + inter + D + gate
// Barrier schedule (wave-locality derived):
//   attL rows [16w,16w+16) produced AND consumed by wave w -> no barrier
//   between att and Y/I MFMA. Barrier needed only before BLb is overwritten
//   (other waves' att-MFMA read BLb as B-operand). BLb y-rows are wave-local
//   to the gate epilogue -> no final barrier.
__global__ __launch_bounds__(256, 3)
void chunk_y_k(const ushort_t* __restrict__ xs, const ushort_t* __restrict__ bcc,
               ushort_t* zio,
               const float* __restrict__ dtv, const float* __restrict__ dalog,
               const ushort_t* __restrict__ statesT, const float* __restrict__ Dp)
{
    const int c = blockIdx.x, h = blockIdx.y, b = blockIdx.z;
    __shared__ __align__(16) ushort_t CLb [64 * 72];  // C[t][n] n-contig
    __shared__ __align__(16) ushort_t BLb [64 * 72];  // B[s][n] n-contig -> ybuf[t][p]
    __shared__ __align__(16) ushort_t xsT [64 * 72];  // xs^T [p][t^sw] t-contig (swizzled)
    __shared__ __align__(16) ushort_t attL[64 * 72];  // att[t][s] s-contig
    __shared__ float cum[64], wdt[64];
    const int tid = threadIdx.x;
    const int ts = tid >> 2, q4 = (tid & 3) * 16;
    const int l = c * QCH + ts;
    const int tswz = ts ^ ((tid & 3) << 4);
    const float Dh = Dp[h];
    { // x: load precomputed conv+silu xs slice, transposed store (swizzled)
        const int ch0 = h * HEADDIM + q4;
        const ushort_t* rp = xs + ((size_t)b * SEQ + l) * 1024 + ch0;
        union { uint4 u; ushort_t s[8]; } u0, u1;
        u0.u = *(const uint4*)rp; u1.u = *(const uint4*)(rp + 8);
#pragma unroll
        for (int i = 0; i < 8; i++) {
            xsT[(q4 + i) * 72 + tswz]     = u0.s[i];
            xsT[(q4 + 8 + i) * 72 + tswz] = u1.s[i];
        }
    }
    { // B, C: plain copies from precomputed bcc
        const ushort_t* rp = bcc + ((size_t)b * SEQ + l) * 128;
        *(uint4*)&BLb[ts * 72 + q4]     = *(const uint4*)(rp + q4);
        *(uint4*)&BLb[ts * 72 + q4 + 8] = *(const uint4*)(rp + q4 + 8);
        *(uint4*)&CLb[ts * 72 + q4]     = *(const uint4*)(rp + 64 + q4);
        *(uint4*)&CLb[ts * 72 + q4 + 8] = *(const uint4*)(rp + 64 + q4 + 8);
    }
    if (tid < 64) {
        size_t gl = (size_t)h * MROWS + (size_t)b * SEQ + c * QCH + tid;   // [head][row] planes
        float v = dalog[gl];
#pragma unroll
        for (int off = 1; off < 64; off <<= 1) {
            float u = __shfl_up(v, off, 64);
            if (tid >= off) v += u;
        }
        cum[tid] = v;
        wdt[tid] = dtv[gl];
    }
    __syncthreads();
    const int wave = tid >> 6, lane = tid & 63;
    const int quad = lane >> 4, l16 = lane & 15;
    {
        f32x4 sacc[4];
#pragma unroll
        for (int j = 0; j < 4; j++) sacc[j] = (f32x4){0.f, 0.f, 0.f, 0.f};
#pragma unroll
        for (int kk = 0; kk < 64; kk += 32) {
            bf16x8 af = *(const bf16x8*)(&CLb[(wave * 16 + l16) * 72 + kk + quad * 8]);
#pragma unroll
            for (int j = 0; j < 4; j++) {
                bf16x8 bf_ = *(const bf16x8*)(&BLb[(j * 16 + l16) * 72 + kk + quad * 8]);
                sacc[j] = __builtin_amdgcn_mfma_f32_16x16x32_bf16(af, bf_, sacc[j], 0, 0, 0);
            }
        }
#pragma unroll
        for (int r = 0; r < 4; r++) {
            const int t = wave * 16 + quad * 4 + r;
            const float ct = cum[t];
#pragma unroll
            for (int j = 0; j < 4; j++) {
                const int s = j * 16 + l16;
                float a = (s <= t) ? sacc[j][r] * __expf(ct - cum[s]) * wdt[s] : 0.f;
                attL[t * 72 + s] = f2bfu(a);
            }
        }
    }
    // no barrier: attL rows are wave-local; Y/I MFMA starts immediately
    {
        f32x4 accY[4], accI[4];
#pragma unroll
        for (int j = 0; j < 4; j++) { accY[j] = (f32x4){0.f, 0.f, 0.f, 0.f}; accI[j] = (f32x4){0.f, 0.f, 0.f, 0.f}; }
        const ushort_t* spg = statesT + ((size_t)(c * BATCH + b) * NHEADS + h) * (HEADDIM * DSTATE);
#pragma unroll
        for (int kk = 0; kk < 64; kk += 32) {
            bf16x8 a2 = *(const bf16x8*)(&attL[(wave * 16 + l16) * 72 + kk + quad * 8]);
            bf16x8 a3 = *(const bf16x8*)(&CLb [(wave * 16 + l16) * 72 + kk + quad * 8]);
#pragma unroll
            for (int j = 0; j < 4; j++) {
                bf16x8 b2 = *(const bf16x8*)(&xsT[(j * 16 + l16) * 72 + ((kk + quad * 8) ^ ((j & 3) << 4))]);
                accY[j] = __builtin_amdgcn_mfma_f32_16x16x32_bf16(a2, b2, accY[j], 0, 0, 0);
                bf16x8 b3 = *(const bf16x8*)(spg + (j * 16 + l16) * 64 + kk + quad * 8);
                accI[j] = __builtin_amdgcn_mfma_f32_16x16x32_bf16(a3, b3, accI[j], 0, 0, 0);
            }
        }
        __syncthreads();   // all waves done reading BLb (att B-operand) before overwrite
#pragma unroll
        for (int r = 0; r < 4; r++) {
            const int t = wave * 16 + quad * 4 + r;
            const float et = __expf(cum[t]);
#pragma unroll
            for (int j = 0; j < 4; j++) {
                const int p = j * 16 + l16;
                float xv = bf2f(xsT[p * 72 + (t ^ ((j & 3) << 4))]);
                float y = accY[j][r] + et * accI[j][r] + Dh * xv;
                BLb[t * 72 + p] = f2bfu(y);
            }
        }
    }
    // no barrier: BLb y-rows [16w,16w+16) are wave-local to the gate below
    {
        ushort_t* zrow = zio + ((size_t)b * SEQ + l) * DINNER + h * HEADDIM + q4;
        float zv[16], yv[16], o[16];
        bf8_to_f(zrow, zv); bf8_to_f(zrow + 8, zv + 8);
        bf8_to_f(&BLb[ts * 72 + q4], yv); bf8_to_f(&BLb[ts * 72 + q4 + 8], yv + 8);
#pragma unroll
        for (int j = 0; j < 16; j++) {
            float z = zv[j];
            o[j] = yv[j] * z * sigmoidf_(z);
        }
        *(uint4*)(zrow)     = f8_to_bf(o);
        *(uint4*)(zrow + 8) = f8_to_bf(o + 8);
    }
}

// ---------------------------------------------------------------- launch
extern "C" void kernel_launch(void* const* d_in, const int* in_sizes, int n_in,
                              void* d_out, int out_size, void* d_ws, size_t ws_size,
                              hipStream_t stream)
{
    const float* x      = (const float*)d_in[0];
    const float* W_in   = (const float*)d_in[1];
    const float* conv_w = (const float*)d_in[2];
    const float* conv_b = (const float*)d_in[3];
    const float* dt_b   = (const float*)d_in[4];
    const float* A_log  = (const float*)d_in[5];
    const float* Dp     = (const float*)d_in[6];
    const float* nw     = (const float*)d_in[7];
    const float* W_out  = (const float*)d_in[8];
    float* out = (float*)d_out;                    // (2,4096,512) fp32

    // ---- workspace (48 MiB high-water) ----
    // [0,16M): zbuf (z -> gated y, in place)
    // [16M,32M): xs (post-conv+silu x, bf16) — written by conv_k
    // [32M,48M): xpre (pre-conv x from gemm0; dead after conv_k) -> statesT
    char* w = (char*)d_ws;
    ushort_t* zbuf    = (ushort_t*)(w);
    ushort_t* xs      = (ushort_t*)(w + 16777216);
    ushort_t* xpre    = (ushort_t*)(w + 33554432);
    ushort_t* statesT = (ushort_t*)(w + 33554432);  // overwrites dead xpre
    // ---- d_out (16.78 MB fp32) doubles as scratch until GEMM2 overwrites it ----
    char* dscr = (char*)d_out;
    ushort_t* xpbc  = (ushort_t*)(dscr);                // [0, 2M): pre-conv B|C
    float*    dtv   = (float*)(dscr + 2097152);         // [2M, 2.5M): [head][row] planes
    float*    dalog = (float*)(dscr + 2621440);         // [2.5M, 3M): [head][row] planes
    float*    cdec  = (float*)(dscr + 3145728);         // [3M, 3M+16K)
    ushort_t* WinT  = (ushort_t*)(dscr + 4194304);      // [4M, 6.25M): W_in^T padded (dead after gemm0)
    ushort_t* bcc   = (ushort_t*)(dscr + 4194304);      // [4M, 6M): post-conv B|C (after gemm0)
    ushort_t* WoutT = (ushort_t*)(dscr + 6815744);      // [6.5M, 7.5M): W_out^T*nw (survives to gemm1)
    ushort_t* xb    = (ushort_t*)(dscr + 8388608);      // [8M, 16M): x bf16 (dead before gemm2)

    // prep: cast x + W_in^T + W_out^T*nw, one launch (blocks co-schedule)
    prep_k<<<2048 + (NPROJ_PAD / 32) * (DMODEL / 32) + (DMODEL / 32) * (DINNER / 32), 256, 0, stream>>>(
        x, xb, W_in, WinT, W_out, WoutT, nw);
    gemm_k<0><<<dim3(NPROJ_PAD / 128, MROWS / 128), 256, 0, stream>>>(
        xb, WinT, zbuf, xpre, xpbc, dtv, dalog, dt_b, A_log, nullptr,
        MROWS, NPROJ, DMODEL);
    // WinT dead; bcc overwrites its region. conv: B/C conv + x conv, one launch
    conv_k<<<512 + 256, 256, 0, stream>>>(xpbc, xpre, conv_w, conv_b, bcc, xs);
    // xpre dead; statesT overwrites its region
    chunk_state_k<<<dim3(NCHUNK, NHEADS, BATCH), 256, 0, stream>>>(
        xs, bcc, dtv, dalog, statesT, cdec);
    scan_combine_k<<<BATCH * NHEADS * 8, 128, 0, stream>>>(statesT, cdec);
    chunk_y_k<<<dim3(NCHUNK, NHEADS, BATCH), 256, 0, stream>>>(
        xs, bcc, zbuf, dtv, dalog, statesT, Dp);
    // RMSNorm fused into gemm_k<1>
    gemm_k<1><<<dim3(DMODEL / 64, MROWS / 128), 256, 0, stream>>>(
        zbuf, WoutT, nullptr, nullptr, nullptr, nullptr, nullptr, nullptr,
        nullptr, out, MROWS, DMODEL, DINNER);
}